// Round 5
// baseline (4305.198 us; speedup 1.0000x reference)
//
#include <hip/hip_runtime.h>
#include <hip/hip_bf16.h>

#define BATCH 128
#define SEQ   1024
#define INDIM 256
#define HID   1024
#define NGATE 4096   // 4*HID
#define KTOT  1280   // INDIM + HID
#define OUTD  256
#define NKK   40     // total K-steps of 32 (1280/32)
#define XKK   8      // k-steps covering the x part (256/32)
#define HKK   32     // k-steps covering the h part
#define NBG   8      // batch groups
#define ROWS  16     // batch rows per group
#define NSL   32     // WGs per group
#define JCOLS 32     // h-columns per WG

typedef __attribute__((ext_vector_type(8))) short s16x8;
typedef __attribute__((ext_vector_type(4))) float f32x4;

__device__ __forceinline__ unsigned short f2bf(float f) {
    unsigned int u = __float_as_uint(f);
    u += 0x7FFFu + ((u >> 16) & 1u);
    return (unsigned short)(u >> 16);
}
__device__ __forceinline__ float sigmoidf_(float x) {
    return 1.0f / (1.0f + __expf(-x));
}
__device__ __forceinline__ float tanhf_(float x) {
    return 1.0f - 2.0f / (1.0f + __expf(2.0f * x));
}

// ---------------------------------------------------------------------------
// Prep 1: WT[n][k] bf16 (transposed, concatenated [Wx;Wh])
// ---------------------------------------------------------------------------
__global__ __launch_bounds__(256) void prep_wt(const float* __restrict__ Wx,
                                               const float* __restrict__ Wh,
                                               unsigned short* __restrict__ WT) {
    __shared__ float tile[64][65];
    int k0 = blockIdx.x * 64;
    int n0 = blockIdx.y * 64;
    for (int idx = threadIdx.x; idx < 64 * 64; idx += 256) {
        int kk = idx >> 6, nn = idx & 63;
        int k = k0 + kk;
        float v = (k < INDIM) ? Wx[(size_t)k * NGATE + (n0 + nn)]
                              : Wh[(size_t)(k - INDIM) * NGATE + (n0 + nn)];
        tile[kk][nn] = v;
    }
    __syncthreads();
    for (int idx = threadIdx.x; idx < 64 * 64; idx += 256) {
        int nn = idx >> 6, kk = idx & 63;
        WT[(size_t)(n0 + nn) * KTOT + (k0 + kk)] = f2bf(tile[kk][nn]);
    }
}

// ---------------------------------------------------------------------------
// Prep 2: x fp32 -> bf16; h0 = (tag0|bf16(0)) = 0; h1 = 0xFFFF0000 sentinel.
// Tagged-h format: word = (step_tag << 16) | bf16.  Valid tags are 0..1024,
// so the 0xFFFF sentinel (and the harness's 0xAAAA poison) never match.
// ---------------------------------------------------------------------------
__global__ __launch_bounds__(256) void prep_x(const float* __restrict__ x,
                                              unsigned short* __restrict__ xb,
                                              unsigned int* __restrict__ h0,
                                              unsigned int* __restrict__ h1) {
    int gid = blockIdx.x * blockDim.x + threadIdx.x;
    int stride = gridDim.x * blockDim.x;
    const int N4 = BATCH * SEQ * INDIM / 4;
    const float4* xv = reinterpret_cast<const float4*>(x);
    uint2* xo = reinterpret_cast<uint2*>(xb);
    for (int i = gid; i < N4; i += stride) {
        float4 v = xv[i];
        uint2 o;
        o.x = (unsigned)f2bf(v.x) | ((unsigned)f2bf(v.y) << 16);
        o.y = (unsigned)f2bf(v.z) | ((unsigned)f2bf(v.w) << 16);
        xo[i] = o;
    }
    const int NH = BATCH * HID;
    for (int i = gid; i < NH; i += stride) {
        h0[i] = 0u;            // tag 0, value bf16(0)
        h1[i] = 0xFFFF0000u;   // sentinel tag
    }
}

// ---------------------------------------------------------------------------
// Persistent LSTM, tagged-data sync (no flags, no fences, no census).
// 256 WGs x 256 thr; WG=(bg,ns): rows bg*16..+16, h-cols ns*32..+32, 4 gates.
// B-fragments register-resident.  h exchanged as (tag|bf16) dwords via
// relaxed agent-scope atomics; consumers poll the data words directly.
// ---------------------------------------------------------------------------
__global__ __launch_bounds__(256, 1) void lstm_persist(
    const unsigned short* __restrict__ xb,   // [B][S][INDIM] bf16
    const unsigned short* __restrict__ WT,   // [NGATE][KTOT] bf16
    unsigned int* __restrict__ h0,           // [B][HID] tagged dwords
    unsigned int* __restrict__ h1,           // [B][HID] tagged dwords
    const float* __restrict__ bias) {        // [NGATE]

    __shared__ unsigned short xbuf0[XKK * 512];  // 8 KB, swizzled slots
    __shared__ unsigned short xbuf1[XKK * 512];  // 8 KB
    __shared__ unsigned short hbuf[HKK * 512];   // 32 KB, swizzled slots
    __shared__ float gex[4 * ROWS * JCOLS];      // 8 KB

    const int tid  = threadIdx.x;
    const int wave = tid >> 6, lane = tid & 63;
    const int lr = lane & 15, kq = lane >> 4;
    const int bg = blockIdx.x & 7;
    const int ns = blockIdx.x >> 3;
    const int b0 = bg * ROWS;
    const int j0 = ns * JCOLS;

    // ---- B fragments into registers (gate=wave, cols j0..j0+31, full K) ----
    s16x8 b0r[NKK], b1r[NKK];
    {
        const unsigned short* base0 =
            WT + ((size_t)(wave * HID + j0 + lr)) * KTOT + kq * 8;
        const unsigned short* base1 = base0 + (size_t)16 * KTOT;
#pragma unroll
        for (int kk = 0; kk < NKK; kk++) {
            b0r[kk] = *reinterpret_cast<const s16x8*>(base0 + kk * 32);
            b1r[kk] = *reinterpret_cast<const s16x8*>(base1 + kk * 32);
        }
    }

    // ---- epilogue constants ----
    const int ecol = tid & 31, erow0 = tid >> 5, erow1 = erow0 + 8;
    const int j = j0 + ecol;
    const float bf = bias[0 * HID + j], bi = bias[1 * HID + j],
                bgg = bias[2 * HID + j], bo = bias[3 * HID + j];
    float c0 = 0.f, c1 = 0.f;

    // ---- x staging addressing (linear LDS dest, inverse-swizzled source) ----
    const int srow = lane >> 2;
    const int skq = ((lane & 3) - ((lane >> 3) & 3)) & 3;
    const unsigned short* xsrc =
        xb + (size_t)(b0 + srow) * SEQ * INDIM + skq * 8;
    // MFMA A-read slot for lane (lr,kq): p = row*4 + ((kq + row>>1) & 3)
    const int p_l = lr * 4 + ((kq + (lr >> 1)) & 3);

    // ---- tagged-h consumer addressing: thread -> (row = tid>>4, k4 = tid&15)
    // k4 covers h-elems k4*2, k4*2+1 of each 32-elem slice (one 8B load).
    const int hrow = tid >> 4, hk4 = tid & 15;
    const int hkq = hk4 >> 2;
    const int hp = hrow * 4 + ((hkq + (hrow >> 1)) & 3);
    unsigned int* hb32 = (unsigned int*)hbuf;
    const int hdst = hp * 4 + (hk4 & 3);             // dword within slice (256/slice)
    const size_t hsrc = (size_t)(b0 + hrow) * (HID / 2) + hk4;  // ull index

    // ---- prologue: stage x for t=0 ----
#pragma unroll
    for (int q = 0; q < 2; q++) {
        int kk = 2 * wave + q;
        __builtin_amdgcn_global_load_lds(
            (const __attribute__((address_space(1))) void*)(xsrc + (size_t)kk * 32),
            (__attribute__((address_space(3))) void*)(xbuf0 + kk * 512), 16, 0, 0);
    }
    __syncthreads();

    for (int t = 0; t < SEQ; t++) {
        const unsigned int* hin = (t & 1) ? h1 : h0;
        unsigned int* hout      = (t & 1) ? h0 : h1;
        unsigned short* xcur    = (t & 1) ? xbuf1 : xbuf0;
        unsigned short* xnxt    = (t & 1) ? xbuf0 : xbuf1;

        // ---- x-part MFMA ----
        f32x4 acc0 = {0.f, 0.f, 0.f, 0.f};
        f32x4 acc1 = {0.f, 0.f, 0.f, 0.f};
        {
            const unsigned short* ax = xcur + p_l * 8;
#pragma unroll
            for (int kk = 0; kk < XKK; kk++) {
                s16x8 a = *reinterpret_cast<const s16x8*>(ax + kk * 512);
                acc0 = __builtin_amdgcn_mfma_f32_16x16x32_bf16(a, b0r[kk], acc0, 0, 0, 0);
                acc1 = __builtin_amdgcn_mfma_f32_16x16x32_bf16(a, b1r[kk], acc1, 0, 0, 0);
            }
        }

        // ---- fire-and-forget: stage x for t+1 ----
        if (t + 1 < SEQ) {
#pragma unroll
            for (int q = 0; q < 2; q++) {
                int kk = 2 * wave + q;
                __builtin_amdgcn_global_load_lds(
                    (const __attribute__((address_space(1))) void*)(xsrc + (size_t)(t + 1) * INDIM + kk * 32),
                    (__attribute__((address_space(3))) void*)(xnxt + kk * 512), 16, 0, 0);
            }
        }

        // ---- tagged h fetch: poll data words until tag == t, then unpack ----
        {
            const unsigned long long* src =
                (const unsigned long long*)hin + hsrc;
            const unsigned exp = (unsigned)t;
            unsigned long long w[4][8];
#pragma unroll
            for (int g = 0; g < 4; g++)
#pragma unroll
                for (int i = 0; i < 8; i++)
                    w[g][i] = __hip_atomic_load(src + (size_t)(g * 8 + i) * 16,
                                                __ATOMIC_RELAXED,
                                                __HIP_MEMORY_SCOPE_AGENT);
#pragma unroll
            for (int g = 0; g < 4; g++) {
                for (;;) {
                    unsigned ok = 1u;
#pragma unroll
                    for (int i = 0; i < 8; i++) {
                        unsigned hi = (unsigned)(w[g][i] >> 48);
                        unsigned mid = (unsigned)(w[g][i] >> 16) & 0xFFFFu;
                        ok &= (unsigned)(hi == exp) & (unsigned)(mid == exp);
                    }
                    if (ok) break;
#pragma unroll
                    for (int i = 0; i < 8; i++)
                        w[g][i] = __hip_atomic_load(src + (size_t)(g * 8 + i) * 16,
                                                    __ATOMIC_RELAXED,
                                                    __HIP_MEMORY_SCOPE_AGENT);
                }
#pragma unroll
                for (int i = 0; i < 8; i++) {
                    int sl = g * 8 + i;
                    unsigned lo = (unsigned)w[g][i];
                    unsigned hi2 = (unsigned)(w[g][i] >> 32);
                    hb32[sl * 256 + hdst] = (lo & 0xFFFFu) | (hi2 << 16);
                }
            }
        }
        __syncthreads();   // B2: hbuf ready

        // ---- h-part MFMA ----
        {
            const unsigned short* ah = hbuf + p_l * 8;
#pragma unroll
            for (int kk = 0; kk < HKK; kk++) {
                s16x8 a = *reinterpret_cast<const s16x8*>(ah + kk * 512);
                acc0 = __builtin_amdgcn_mfma_f32_16x16x32_bf16(a, b0r[XKK + kk], acc0, 0, 0, 0);
                acc1 = __builtin_amdgcn_mfma_f32_16x16x32_bf16(a, b1r[XKK + kk], acc1, 0, 0, 0);
            }
        }

        // ---- gate exchange (C/D: col=lane&15, row=(lane>>4)*4+r) ----
#pragma unroll
        for (int r = 0; r < 4; r++) {
            int row = kq * 4 + r;
            gex[wave * 512 + row * 32 + lr]      = acc0[r];
            gex[wave * 512 + row * 32 + 16 + lr] = acc1[r];
        }
        __syncthreads();   // B3: gex ready (also fences hbuf reads before next scatter)

        // ---- activations + c update + tagged h stores ----
        const unsigned otag = (unsigned)(t + 1) << 16;
        {
            float ff = sigmoidf_(gex[0 * 512 + erow0 * 32 + ecol] + bf);
            float ii = sigmoidf_(gex[1 * 512 + erow0 * 32 + ecol] + bi);
            float gg = tanhf_(gex[2 * 512 + erow0 * 32 + ecol] + bgg);
            float oo = sigmoidf_(gex[3 * 512 + erow0 * 32 + ecol] + bo);
            c0 = ff * c0 + ii * gg;
            unsigned word = otag | (unsigned)f2bf(oo * tanhf_(c0));
            __hip_atomic_store(hout + (size_t)(b0 + erow0) * HID + j, word,
                               __ATOMIC_RELAXED, __HIP_MEMORY_SCOPE_AGENT);
        }
        {
            float ff = sigmoidf_(gex[0 * 512 + erow1 * 32 + ecol] + bf);
            float ii = sigmoidf_(gex[1 * 512 + erow1 * 32 + ecol] + bi);
            float gg = tanhf_(gex[2 * 512 + erow1 * 32 + ecol] + bgg);
            float oo = sigmoidf_(gex[3 * 512 + erow1 * 32 + ecol] + bo);
            c1 = ff * c1 + ii * gg;
            unsigned word = otag | (unsigned)f2bf(oo * tanhf_(c1));
            __hip_atomic_store(hout + (size_t)(b0 + erow1) * HID + j, word,
                               __ATOMIC_RELAXED, __HIP_MEMORY_SCOPE_AGENT);
        }
        // no barrier, no flag: tag arrives with the data.
    }
}

// ---------------------------------------------------------------------------
// Final FC: h0 holds tagged h_T (tag 1024); use low 16 bits.
// ---------------------------------------------------------------------------
__global__ __launch_bounds__(256) void final_fc(const unsigned int* __restrict__ h,
                                                const float* __restrict__ Wfc,
                                                const float* __restrict__ bfc,
                                                float* __restrict__ out) {
    int b = blockIdx.x;
    int o = threadIdx.x;
    const unsigned int* hr = h + (size_t)b * HID;
    float acc = bfc[o];
#pragma unroll 8
    for (int k = 0; k < HID; k++) {
        acc += __uint_as_float(hr[k] << 16) * Wfc[(size_t)k * OUTD + o];
    }
    out[(size_t)b * OUTD + o] = acc;
}

// ---------------------------------------------------------------------------
extern "C" void kernel_launch(void* const* d_in, const int* in_sizes, int n_in,
                              void* d_out, int out_size, void* d_ws, size_t ws_size,
                              hipStream_t stream) {
    const float* x    = (const float*)d_in[0];
    const float* Wx   = (const float*)d_in[1];
    const float* Wh   = (const float*)d_in[2];
    const float* bias = (const float*)d_in[3];
    const float* Wfc  = (const float*)d_in[4];
    const float* bfc  = (const float*)d_in[5];
    float* out = (float*)d_out;

    char* ws = (char*)d_ws;
    // ws layout (bytes):
    //   WT : 4096*1280*2    = 10,485,760  @ 0
    //   xb : 128*1024*256*2 = 67,108,864  @ 10,485,760
    //   h0 : 128*1024*4     =    524,288  @ 77,594,624   (tagged dwords)
    //   h1 : 128*1024*4     =    524,288  @ 78,118,912   -> total 78,643,200
    unsigned short* WT = (unsigned short*)(ws);
    unsigned short* xb = (unsigned short*)(ws + 10485760);
    unsigned int* h0   = (unsigned int*)(ws + 77594624);
    unsigned int* h1   = (unsigned int*)(ws + 78118912);

    hipLaunchKernelGGL(prep_wt, dim3(KTOT / 64, NGATE / 64), dim3(256), 0, stream,
                       Wx, Wh, WT);
    hipLaunchKernelGGL(prep_x, dim3(1024), dim3(256), 0, stream, x, xb, h0, h1);

    hipLaunchKernelGGL(lstm_persist, dim3(256), dim3(256), 0, stream,
                       xb, WT, h0, h1, bias);

    // 1024 steps -> final tagged h lands in h0
    hipLaunchKernelGGL(final_fc, dim3(128), dim3(256), 0, stream, h0, Wfc, bfc, out);
}